// Round 3
// baseline (79.069 us; speedup 1.0000x reference)
//
#include <hip/hip_runtime.h>
#include <hip/hip_bf16.h>
#include <cstdint>

typedef __bf16 bf16_t;
typedef __attribute__((ext_vector_type(4))) __bf16 bf16x4;
typedef __attribute__((ext_vector_type(8))) __bf16 bf16x8;
typedef __attribute__((ext_vector_type(4))) float f32x4;

#define DIM 256
#define TINV 10.0f
// TINV * log2(e): e = exp(S/T) == exp2(S * EXP2C)
#define EXP2C 14.426950408889634f
#define BM 128
#define BN 128
#define BK 64

// Kernel 1: row-normalize y (f32) -> yn (bf16); zero rowsum accumulator.
// One row per wave, float4 per lane (64 lanes x 4 = 256 = DIM).
__global__ void nt_normalize(const float* __restrict__ y, bf16_t* __restrict__ yn,
                             float* __restrict__ rowsum, int N) {
    int tid = threadIdx.x;
    int wave = tid >> 6, lane = tid & 63;
    int row = blockIdx.x * 4 + wave;
    float4 v = ((const float4*)(y + (size_t)row * DIM))[lane];
    float ss = v.x * v.x + v.y * v.y + v.z * v.z + v.w * v.w;
#pragma unroll
    for (int off = 1; off < 64; off <<= 1) ss += __shfl_xor(ss, off);
    float inv = 1.0f / fmaxf(sqrtf(ss), 1e-8f);
    bf16x4 o;
    o[0] = (bf16_t)(v.x * inv);
    o[1] = (bf16_t)(v.y * inv);
    o[2] = (bf16_t)(v.z * inv);
    o[3] = (bf16_t)(v.w * inv);
    ((bf16x4*)(yn + (size_t)row * DIM))[lane] = o;
    if (lane == 0) rowsum[row] = 0.0f;
}

// Kernel 2: fused sim-GEMM + exp + row-sum + pos capture, SYMMETRIC triangular grid.
// Exactly nt*(nt+1)/2 blocks; block t maps to (by<=bx). Off-diagonal tiles add
// their exp-tile to rowsum[row] (col-reduce) AND rowsum[col] (row-reduce).
// 128x128 tile, 4 waves (2x2), each wave 64x64 (4x4 frags of 16x16x32 bf16).
// Double-buffered LDS (2-phase T3): issue next tile's global_load_lds BEFORE
// computing current; single barrier per iter drains prefetch under compute.
// LDS tiles XOR-swizzled via pre-swizzled global source (rule #21).
__launch_bounds__(256, 2)
__global__ void nt_gemm(const bf16_t* __restrict__ yn, float* __restrict__ rowsum,
                        float* __restrict__ posterm, int N) {
    const int nt = N / BN;
    const int T = nt * (nt + 1) / 2;
    // bijective XCD-chunked swizzle (m204): consecutive-in-XCD blocks share a row strip
    int nwg = T;
    int orig = blockIdx.x;
    int q = nwg >> 3, r = nwg & 7;
    int xcd = orig & 7, loc = orig >> 3;
    int t = (xcd < r ? xcd * (q + 1) : r * (q + 1) + (xcd - r) * q) + loc;
    // triangular index -> (by, bx), by <= bx  (count from bottom-right corner)
    int s = T - 1 - t;
    float f = sqrtf(8.0f * (float)s + 1.0f);
    int j = (int)((f - 1.0f) * 0.5f);
    while ((j + 1) * (j + 2) / 2 <= s) ++j;
    while (j * (j + 1) / 2 > s) --j;
    int k = s - j * (j + 1) / 2;
    int by = nt - 1 - j, bx = nt - 1 - k;

    __shared__ __align__(16) bf16_t As[2][BM][BK];
    __shared__ __align__(16) bf16_t Bs[2][BN][BK];
    int r0 = by * BM, c0 = bx * BN;
    int tid = threadIdx.x;
    int wave = tid >> 6, lane = tid & 63;
    int wr = wave >> 1, wc = wave & 1;
    int l16 = lane & 15, lg = lane >> 4;

    // staging addresses for this thread (chunk = 16B = 8 bf16)
    int cbase0 = wave * 64;          // wave-uniform base chunk within a 256-chunk group
    f32x4 acc[4][4] = {};

#define STAGE(buf, k0)                                                              \
    {                                                                               \
        _Pragma("unroll")                                                           \
        for (int it = 0; it < 4; ++it) {                                            \
            int cbase = it * 256 + cbase0;                                          \
            int c = cbase + lane;                                                   \
            int row = c >> 3, cc = c & 7;                                           \
            int gc = cc ^ (row & 7);                                                \
            const bf16_t* srcA = yn + (size_t)(r0 + row) * DIM + (k0) + gc * 8;     \
            __builtin_amdgcn_global_load_lds(                                       \
                (const __attribute__((address_space(1))) uint32_t*)srcA,            \
                (__attribute__((address_space(3))) uint32_t*)                       \
                    ((char*)&As[buf][0][0] + cbase * 16), 16, 0, 0);                \
            const bf16_t* srcB = yn + (size_t)(c0 + row) * DIM + (k0) + gc * 8;     \
            __builtin_amdgcn_global_load_lds(                                       \
                (const __attribute__((address_space(1))) uint32_t*)srcB,            \
                (__attribute__((address_space(3))) uint32_t*)                       \
                    ((char*)&Bs[buf][0][0] + cbase * 16), 16, 0, 0);                \
        }                                                                           \
    }

    STAGE(0, 0);
    __syncthreads();                    // prologue drain: buf0 ready

#pragma unroll
    for (int it4 = 0; it4 < DIM / BK; ++it4) {
        int cur = it4 & 1;
        if (it4 < DIM / BK - 1) STAGE(cur ^ 1, (it4 + 1) * BK);   // prefetch next
#pragma unroll
        for (int kk = 0; kk < 2; ++kk) {
            bf16x8 af[4], bfr[4];
#pragma unroll
            for (int m = 0; m < 4; ++m) {
                int row = wr * 64 + m * 16 + l16;
                int kc = kk * 4 + lg;
                af[m] = *(const bf16x8*)((const char*)&As[cur][0][0] +
                                         row * (BK * 2) + ((kc ^ (row & 7)) * 16));
            }
#pragma unroll
            for (int n = 0; n < 4; ++n) {
                int row = wc * 64 + n * 16 + l16;
                int kc = kk * 4 + lg;
                bfr[n] = *(const bf16x8*)((const char*)&Bs[cur][0][0] +
                                          row * (BK * 2) + ((kc ^ (row & 7)) * 16));
            }
#pragma unroll
            for (int m = 0; m < 4; ++m)
#pragma unroll
                for (int n = 0; n < 4; ++n)
                    acc[m][n] = __builtin_amdgcn_mfma_f32_16x16x32_bf16(
                        af[m], bfr[n], acc[m][n], 0, 0, 0);
        }
        if (it4 < DIM / BK - 1) __syncthreads();   // drains prefetch; both bufs settled
    }

    // Epilogue. C/D layout (m89): col = lane&15, row = (lane>>4)*4 + reg.
    if (by == bx) {
        // Diagonal tile: mask diagonal, capture pos pair, row-sum only.
#pragma unroll
        for (int m = 0; m < 4; ++m) {
#pragma unroll
            for (int r2 = 0; r2 < 4; ++r2) {
                int grow = r0 + wr * 64 + m * 16 + lg * 4 + r2;
                float ssum = 0.0f;
#pragma unroll
                for (int n = 0; n < 4; ++n) {
                    int gcol = c0 + wc * 64 + n * 16 + l16;
                    float S = acc[m][n][r2];
                    float e = __builtin_amdgcn_exp2f(S * EXP2C);
                    if (gcol == grow) e = 0.0f;                        // mask diagonal
                    if (gcol == (grow ^ 1)) posterm[grow] = -S * TINV; // positive pair
                    ssum += e;
                }
                ssum += __shfl_xor(ssum, 1);
                ssum += __shfl_xor(ssum, 2);
                ssum += __shfl_xor(ssum, 4);
                ssum += __shfl_xor(ssum, 8);
                if (l16 == 0) atomicAdd(&rowsum[grow], ssum);
            }
        }
    } else {
        // Off-diagonal: row sums for rows r0.., col sums (transposed half) for cols c0..
        float colacc[4] = {0.0f, 0.0f, 0.0f, 0.0f};
#pragma unroll
        for (int m = 0; m < 4; ++m) {
#pragma unroll
            for (int r2 = 0; r2 < 4; ++r2) {
                int grow = r0 + wr * 64 + m * 16 + lg * 4 + r2;
                float ssum = 0.0f;
#pragma unroll
                for (int n = 0; n < 4; ++n) {
                    float e = __builtin_amdgcn_exp2f(acc[m][n][r2] * EXP2C);
                    ssum += e;
                    colacc[n] += e;
                }
                ssum += __shfl_xor(ssum, 1);
                ssum += __shfl_xor(ssum, 2);
                ssum += __shfl_xor(ssum, 4);
                ssum += __shfl_xor(ssum, 8);
                if (l16 == 0) atomicAdd(&rowsum[grow], ssum);
            }
        }
#pragma unroll
        for (int n = 0; n < 4; ++n) {
            colacc[n] += __shfl_xor(colacc[n], 16);
            colacc[n] += __shfl_xor(colacc[n], 32);
        }
        if (lane < 16) {
#pragma unroll
            for (int n = 0; n < 4; ++n)
                atomicAdd(&rowsum[c0 + wc * 64 + n * 16 + l16], colacc[n]);
        }
    }
#undef STAGE
}

// Kernel 3: loss = mean(posterm + log(rowsum))
__global__ void nt_reduce(const float* __restrict__ rowsum, const float* __restrict__ posterm,
                          float* __restrict__ out, int N) {
    __shared__ float part[16];
    int tid = threadIdx.x;
    float s = 0.0f;
    for (int i = tid; i < N; i += 1024)
        s += posterm[i] + logf(rowsum[i]);
#pragma unroll
    for (int off = 32; off; off >>= 1) s += __shfl_down(s, off);
    if ((tid & 63) == 0) part[tid >> 6] = s;
    __syncthreads();
    if (tid == 0) {
        float tot = 0.0f;
#pragma unroll
        for (int w = 0; w < 16; ++w) tot += part[w];
        out[0] = tot / (float)N;
    }
}

extern "C" void kernel_launch(void* const* d_in, const int* in_sizes, int n_in,
                              void* d_out, int out_size, void* d_ws, size_t ws_size,
                              hipStream_t stream) {
    const float* y = (const float*)d_in[0];
    int N = in_sizes[0] / DIM;                 // 8192
    bf16_t* yn = (bf16_t*)d_ws;                // N*DIM bf16 = 4 MB
    float* rowsum = (float*)((char*)d_ws + (size_t)N * DIM * sizeof(bf16_t));
    float* posterm = rowsum + N;
    float* out = (float*)d_out;

    nt_normalize<<<N / 4, 256, 0, stream>>>(y, yn, rowsum, N);
    int nt = N / BN;
    int T = nt * (nt + 1) / 2;                 // triangular grid: no dead blocks
    nt_gemm<<<T, 256, 0, stream>>>(yn, rowsum, posterm, N);
    nt_reduce<<<1, 1024, 0, stream>>>(rowsum, posterm, out, N);
}

// Round 4
// 67.383 us; speedup vs baseline: 1.1734x; 1.1734x over previous
//
#include <hip/hip_runtime.h>
#include <hip/hip_bf16.h>
#include <cstdint>

typedef __bf16 bf16_t;
typedef __attribute__((ext_vector_type(4))) __bf16 bf16x4;
typedef __attribute__((ext_vector_type(8))) __bf16 bf16x8;
typedef __attribute__((ext_vector_type(4))) float f32x4;

#define DIM 256
#define TINV 10.0f
// TINV * log2(e): e = exp(S/T) == exp2(S * EXP2C)
#define EXP2C 14.426950408889634f
#define BM 128
#define BN 128
#define BK 64

// Kernel 1: row-normalize y (f32) -> yn (bf16); zero the loss accumulator.
__global__ void nt_normalize(const float* __restrict__ y, bf16_t* __restrict__ yn,
                             float* __restrict__ out, int N) {
    int tid = threadIdx.x;
    int wave = tid >> 6, lane = tid & 63;
    int row = blockIdx.x * 4 + wave;
    float4 v = ((const float4*)(y + (size_t)row * DIM))[lane];
    float ss = v.x * v.x + v.y * v.y + v.z * v.z + v.w * v.w;
#pragma unroll
    for (int off = 1; off < 64; off <<= 1) ss += __shfl_xor(ss, off);
    float inv = 1.0f / fmaxf(sqrtf(ss), 1e-8f);
    bf16x4 o;
    o[0] = (bf16_t)(v.x * inv);
    o[1] = (bf16_t)(v.y * inv);
    o[2] = (bf16_t)(v.z * inv);
    o[3] = (bf16_t)(v.w * inv);
    ((bf16x4*)(yn + (size_t)row * DIM))[lane] = o;
    if (blockIdx.x == 0 && tid == 0) out[0] = 0.0f;   // zero loss accumulator each launch
}

// Kernel 2: fused sim-GEMM + exp + partial row/col sums + pos capture.
// Triangular grid (by<=bx), NO GLOBAL ATOMICS: tile (by,bx) stores its 128
// row-partials to P[bx][rows of strip by] and (off-diag only) its 128
// col-partials to P[by][cols of strip bx]. Each P element has exactly one
// writer. Single-buffer 32KB LDS staging (R2 structure, best measured).
__launch_bounds__(256, 2)
__global__ void nt_gemm(const bf16_t* __restrict__ yn, float* __restrict__ P,
                        float* __restrict__ posterm, int N) {
    const int nt = N / BN;
    const int T = nt * (nt + 1) / 2;
    // bijective XCD-chunked swizzle (m204)
    int orig = blockIdx.x;
    int q = T >> 3, r = T & 7;
    int xcd = orig & 7, loc = orig >> 3;
    int t = (xcd < r ? xcd * (q + 1) : r * (q + 1) + (xcd - r) * q) + loc;
    // triangular index -> (by, bx), by <= bx (count from bottom-right corner)
    int s = T - 1 - t;
    float f = sqrtf(8.0f * (float)s + 1.0f);
    int j = (int)((f - 1.0f) * 0.5f);
    while ((j + 1) * (j + 2) / 2 <= s) ++j;
    while (j * (j + 1) / 2 > s) --j;
    int k = s - j * (j + 1) / 2;
    int by = nt - 1 - j, bx = nt - 1 - k;

    __shared__ __align__(16) bf16_t As[BM][BK];
    __shared__ __align__(16) bf16_t Bs[BN][BK];
    int r0 = by * BM, c0 = bx * BN;
    int tid = threadIdx.x;
    int wave = tid >> 6, lane = tid & 63;
    int wr = wave >> 1, wc = wave & 1;
    int l16 = lane & 15, lg = lane >> 4;

    f32x4 acc[4][4] = {};

    for (int k0 = 0; k0 < DIM; k0 += BK) {
        if (k0) __syncthreads();   // protect previous iter's LDS reads
        // Stage A,B tiles: 128x64 bf16 = 1024 16B-chunks each; 256 threads x 4 iters.
        // LDS chunk (row, cc) holds global chunk (row, cc ^ (row&7)).
#pragma unroll
        for (int it = 0; it < 4; ++it) {
            int cbase = it * 256 + wave * 64;     // wave-uniform chunk base
            int c = cbase + lane;                 // this lane's chunk
            int row = c >> 3, cc = c & 7;
            int gc = cc ^ (row & 7);
            const bf16_t* srcA = yn + (size_t)(r0 + row) * DIM + k0 + gc * 8;
            __builtin_amdgcn_global_load_lds(
                (const __attribute__((address_space(1))) uint32_t*)srcA,
                (__attribute__((address_space(3))) uint32_t*)((char*)&As[0][0] + cbase * 16),
                16, 0, 0);
            const bf16_t* srcB = yn + (size_t)(c0 + row) * DIM + k0 + gc * 8;
            __builtin_amdgcn_global_load_lds(
                (const __attribute__((address_space(1))) uint32_t*)srcB,
                (__attribute__((address_space(3))) uint32_t*)((char*)&Bs[0][0] + cbase * 16),
                16, 0, 0);
        }
        __syncthreads();   // drains vmcnt before any wave reads LDS

#pragma unroll
        for (int kk = 0; kk < 2; ++kk) {
            bf16x8 af[4], bfr[4];
#pragma unroll
            for (int m = 0; m < 4; ++m) {
                int row = wr * 64 + m * 16 + l16;
                int kc = kk * 4 + lg;
                af[m] = *(const bf16x8*)((const char*)&As[0][0] +
                                         row * (BK * 2) + ((kc ^ (row & 7)) * 16));
            }
#pragma unroll
            for (int n = 0; n < 4; ++n) {
                int row = wc * 64 + n * 16 + l16;
                int kc = kk * 4 + lg;
                bfr[n] = *(const bf16x8*)((const char*)&Bs[0][0] +
                                          row * (BK * 2) + ((kc ^ (row & 7)) * 16));
            }
#pragma unroll
            for (int m = 0; m < 4; ++m)
#pragma unroll
                for (int n = 0; n < 4; ++n)
                    acc[m][n] = __builtin_amdgcn_mfma_f32_16x16x32_bf16(
                        af[m], bfr[n], acc[m][n], 0, 0, 0);
        }
    }

    // Epilogue. C/D layout (m89): col = lane&15, row = (lane>>4)*4 + reg.
    // Per-wave row partials: waves (wr,0) and (wr,1) cover the same 64 rows ->
    // combine the two col-halves via one LDS pass, then single store per row.
    __shared__ float rowpart[2][64];   // [wr][row-in-wave-strip]
    __syncthreads();                   // re-use LDS after last MFMA reads

    if (by == bx) {
        // Diagonal tile: mask diagonal, capture pos pair, row sums only.
#pragma unroll
        for (int m = 0; m < 4; ++m) {
#pragma unroll
            for (int r2 = 0; r2 < 4; ++r2) {
                int lrow = m * 16 + lg * 4 + r2;           // row within wave strip
                int grow = r0 + wr * 64 + lrow;
                float ssum = 0.0f;
#pragma unroll
                for (int n = 0; n < 4; ++n) {
                    int gcol = c0 + wc * 64 + n * 16 + l16;
                    float S = acc[m][n][r2];
                    float e = __builtin_amdgcn_exp2f(S * EXP2C);
                    if (gcol == grow) e = 0.0f;                        // mask diagonal
                    if (gcol == (grow ^ 1)) posterm[grow] = -S * TINV; // positive pair
                    ssum += e;
                }
                ssum += __shfl_xor(ssum, 1);
                ssum += __shfl_xor(ssum, 2);
                ssum += __shfl_xor(ssum, 4);
                ssum += __shfl_xor(ssum, 8);
                if (l16 == 0) {
                    if (wc == 0) rowpart[wr][lrow] = ssum;
                }
            }
        }
        __syncthreads();
        // second col-half adds and stores
#pragma unroll
        for (int m = 0; m < 4; ++m) {
#pragma unroll
            for (int r2 = 0; r2 < 4; ++r2) {
                int lrow = m * 16 + lg * 4 + r2;
                int grow = r0 + wr * 64 + lrow;
                float ssum = 0.0f;
#pragma unroll
                for (int n = 0; n < 4; ++n) {
                    int gcol = c0 + wc * 64 + n * 16 + l16;
                    float S = acc[m][n][r2];
                    float e = __builtin_amdgcn_exp2f(S * EXP2C);
                    if (gcol == grow) e = 0.0f;
                    ssum += e;
                }
                ssum += __shfl_xor(ssum, 1);
                ssum += __shfl_xor(ssum, 2);
                ssum += __shfl_xor(ssum, 4);
                ssum += __shfl_xor(ssum, 8);
                if (l16 == 0 && wc == 1)
                    P[(size_t)bx * N + grow] = rowpart[wr][lrow] + ssum;
            }
        }
    } else {
        // Off-diagonal: row partials -> P[bx][strip by], col partials -> P[by][strip bx].
        float colacc[4] = {0.0f, 0.0f, 0.0f, 0.0f};
        float rowsum_l[16];
#pragma unroll
        for (int m = 0; m < 4; ++m) {
#pragma unroll
            for (int r2 = 0; r2 < 4; ++r2) {
                float ssum = 0.0f;
#pragma unroll
                for (int n = 0; n < 4; ++n) {
                    float e = __builtin_amdgcn_exp2f(acc[m][n][r2] * EXP2C);
                    ssum += e;
                    colacc[n] += e;
                }
                ssum += __shfl_xor(ssum, 1);
                ssum += __shfl_xor(ssum, 2);
                ssum += __shfl_xor(ssum, 4);
                ssum += __shfl_xor(ssum, 8);
                rowsum_l[m * 4 + r2] = ssum;
            }
        }
        // combine the two col-halves (wc) for row sums via LDS
#pragma unroll
        for (int m = 0; m < 4; ++m)
#pragma unroll
            for (int r2 = 0; r2 < 4; ++r2) {
                int lrow = m * 16 + lg * 4 + r2;
                if (l16 == 0 && wc == 0) rowpart[wr][lrow] = rowsum_l[m * 4 + r2];
            }
        __syncthreads();
#pragma unroll
        for (int m = 0; m < 4; ++m)
#pragma unroll
            for (int r2 = 0; r2 < 4; ++r2) {
                int lrow = m * 16 + lg * 4 + r2;
                int grow = r0 + wr * 64 + lrow;
                if (l16 == 0 && wc == 1)
                    P[(size_t)bx * N + grow] = rowpart[wr][lrow] + rowsum_l[m * 4 + r2];
            }
        // col partials: reduce across lg (rows), then across wr via LDS
#pragma unroll
        for (int n = 0; n < 4; ++n) {
            colacc[n] += __shfl_xor(colacc[n], 16);
            colacc[n] += __shfl_xor(colacc[n], 32);
        }
        __shared__ float colpart[2][128];   // [wr][col-in-tile]
        if (lane < 16 && wr == 0) {
#pragma unroll
            for (int n = 0; n < 4; ++n)
                colpart[0][wc * 64 + n * 16 + l16] = colacc[n];
        }
        __syncthreads();
        if (lane < 16 && wr == 1) {
#pragma unroll
            for (int n = 0; n < 4; ++n) {
                int lcol = wc * 64 + n * 16 + l16;
                P[(size_t)by * N + c0 + lcol] = colpart[0][lcol] + colacc[n];
            }
        }
    }
}

// Kernel 3: loss partial = sum over rows of (posterm[r] + log(sum_slots P[s][r]));
// 32 blocks x 256 threads, one row per thread; one atomicAdd per block.
__global__ void nt_reduce(const float* __restrict__ P, const float* __restrict__ posterm,
                          float* __restrict__ out, int N, int nt) {
    int row = blockIdx.x * 256 + threadIdx.x;
    float s = 0.0f;
    for (int j = 0; j < nt; ++j) s += P[(size_t)j * N + row];
    float v = posterm[row] + logf(s);
#pragma unroll
    for (int off = 1; off < 64; off <<= 1) v += __shfl_xor(v, off);
    __shared__ float part[4];
    int wave = threadIdx.x >> 6, lane = threadIdx.x & 63;
    if (lane == 0) part[wave] = v;
    __syncthreads();
    if (threadIdx.x == 0) {
        float tot = part[0] + part[1] + part[2] + part[3];
        atomicAdd(out, tot / (float)N);
    }
}

extern "C" void kernel_launch(void* const* d_in, const int* in_sizes, int n_in,
                              void* d_out, int out_size, void* d_ws, size_t ws_size,
                              hipStream_t stream) {
    const float* y = (const float*)d_in[0];
    int N = in_sizes[0] / DIM;                 // 8192
    int nt = N / BN;                           // 64
    bf16_t* yn = (bf16_t*)d_ws;                // N*DIM bf16 = 4 MB
    float* posterm = (float*)((char*)d_ws + (size_t)N * DIM * sizeof(bf16_t));  // 32 KB
    float* P = posterm + N;                    // nt*N f32 = 2 MB
    float* out = (float*)d_out;

    nt_normalize<<<N / 4, 256, 0, stream>>>(y, yn, out, N);
    int T = nt * (nt + 1) / 2;                 // triangular grid: no dead blocks
    nt_gemm<<<T, 256, 0, stream>>>(yn, P, posterm, N);
    nt_reduce<<<N / 256, 256, 0, stream>>>(P, posterm, out, N, nt);
}